// Round 10
// baseline (37.386 us; speedup 1.0000x reference)
//
#include <hip/hip_runtime.h>

// ROI max-pooling, faithful to the reference (including the buggy min/max
// ordering). feat: [B=4, C=64, H=128, W=128] f32; boxes: [B, N=64, 7] f32
// out: [B, N, C, 7, 7] f32
//
// Round-10: tail-imbalance fix. Block = 512 thr = 8 waves = 2 channels x
// 4 y-SEGMENTS of one box. Rows of the ROI are partitioned exactly across
// segments (no duplicate loads); each wave runs the exact-trip flat walk on
// its segment with a segment-generalized bin state machine (scalar p_cur
// search at ys; epilogue seeds bin p when s_p == ye-1). Per-segment partial
// bin maxes land in colmax[ch][seg][p][x]; stage 2 maxes across segments.
// Max per-wave work drops 4x (~64 row-loads) and 8192 blocks fill 1024
// resident slots in 8 rounds -> scheduler self-balances the drain tail.
// XCD slicing kept: blockIdx.x%8 selects a channel-pair class (2 MB/XCD).

constexpr int Bb = 4, Cc = 64, Hh = 128, Ww = 128, Nn = 64, BOX_DIM = 7;
constexpr int POOL = 7;
constexpr int CH_PER = 2;           // channels per block
constexpr int YS = 4;               // y-segments per block
constexpr int PITCH = Ww + 1;       // 129: breaks power-of-2 bank stride

__global__ __launch_bounds__(512) void roi_pool_kernel(
    const float* __restrict__ feat,
    const float* __restrict__ boxes,
    float* __restrict__ out)
{
    __shared__ float colmax[CH_PER][YS][POOL][PITCH];   // 28896 B

    const int bn   = blockIdx.y;                   // box index (B*N)
    const int b    = bn >> 6;                      // Nn = 64
    const int wave = threadIdx.x >> 6;
    const int lane = threadIdx.x & 63;
    const int ch   = wave & 1;                     // channel within pair
    const int seg  = wave >> 1;                    // y-segment 0..3
    const int c    = blockIdx.x * CH_PER + ch;     // channel

    // --- box decode (same address for all lanes -> broadcast load) ---
    const float* bx = boxes + (size_t)bn * BOX_DIM;
    bool valid = false;
#pragma unroll
    for (int i = 0; i < BOX_DIM; ++i) valid = valid || (bx[i] != 0.0f);

    float x1 = fminf(fmaxf(bx[0], 0.0f), (float)(Ww - 1));
    float y1 = fminf(fmaxf(bx[1], 0.0f), (float)(Hh - 1));
    float x2 = fminf(fmaxf(bx[2], 0.0f), (float)(Ww - 1));
    float y2 = fminf(fmaxf(bx[3], 0.0f), (float)(Hh - 1));
    // reference ordering exactly (sequential updates)
    x1 = fminf(x1, x2);
    x2 = fmaxf(x1, x2);
    y1 = fminf(y1, y2);
    y2 = fmaxf(y1, y2);

    // wave-uniform ints -> scalar control flow everywhere below
    int x1i = __builtin_amdgcn_readfirstlane((int)x1);
    int x2i = __builtin_amdgcn_readfirstlane((int)x2);
    int y1i = __builtin_amdgcn_readfirstlane((int)y1);
    int y2i = __builtin_amdgcn_readfirstlane((int)y2);
    if (x2i == x1i) x2i = x1i + 1;
    if (y2i == y1i) y2i = y1i + 1;
    const int Lh = y2i - y1i;      // 1..127
    const int Lw = x2i - x1i;      // 1..127

    // global bin bounds (uniform)
    int s_[POOL], e_[POOL];
#pragma unroll
    for (int p = 0; p < POOL; ++p) {
        s_[p] = y1i + (p * Lh) / POOL;
        e_[p] = y1i + ((p + 1) * Lh + POOL - 1) / POOL;
    }

    // this wave's exact row partition [ys, ye)
    const int ys = y1i + (seg * Lh) / YS;
    const int ye = y1i + ((seg + 1) * Lh) / YS;

    const float* fp = feat + ((size_t)(b * Cc + c) * Hh) * Ww;

    // --- stage 1: per-lane, per-segment partial column maxes ---
    for (int x0 = 0; x0 < Lw; x0 += 64) {
        const int xoff = x0 + lane;                 // < 128 < PITCH
        const int xcol = x1i + min(xoff, Lw - 1);   // clamped, coalesced

        // init all bins for this (ch,seg,xoff) to -inf
#pragma unroll
        for (int p = 0; p < POOL; ++p)
            colmax[ch][seg][p][xoff] = -INFINITY;

        if (ys < ye) {
            // starting bin: first p with e_p > ys  (scalar, <=6 iters)
            int p_cur = 0;
            while (e_[p_cur] <= ys) ++p_cur;
            int   e_cur = e_[p_cur];
            float cur   = -INFINITY;
            float prev  = -INFINITY;

            const int yl = ye - 1;
            float buf[4];                           // 4-ring, static-indexed
#pragma unroll
            for (int j = 0; j < 4; ++j)
                buf[j] = fp[(size_t)(min(ys + j, yl) * Ww) + xcol];

            int y = ys;
            const int nfull = (ye - ys) >> 2;       // exact-trip: no overshoot
            for (int g = 0; g < nfull; ++g) {
#pragma unroll
                for (int j = 0; j < 4; ++j) {
                    const float v = buf[j];
                    buf[j] = fp[(size_t)(min(y + 4, yl) * Ww) + xcol];
                    while (y >= e_cur) {            // uniform, rarely taken
                        colmax[ch][seg][p_cur][xoff] = cur;
                        ++p_cur;
                        cur   = (s_[p_cur] == y - 1) ? prev : -INFINITY;
                        e_cur = e_[p_cur];          // e_[6] = y2i > y always
                    }
                    cur  = fmaxf(cur, v);
                    prev = v;
                    ++y;
                }
            }
            const int rem = (ye - ys) & 3;          // buf[0..rem-1] hold rows y..
            for (int k = 0; k < rem; ++k) {
                const float v = buf[k];
                while (y >= e_cur) {
                    colmax[ch][seg][p_cur][xoff] = cur;
                    ++p_cur;
                    cur   = (s_[p_cur] == y - 1) ? prev : -INFINITY;
                    e_cur = e_[p_cur];
                }
                cur  = fmaxf(cur, v);
                prev = v;
                ++y;
            }

            // epilogue: flush partial bin; seed bins starting at last row
            colmax[ch][seg][p_cur][xoff] = cur;
#pragma unroll
            for (int p = 1; p < POOL; ++p)
                if (p > p_cur && s_[p] == ye - 1)
                    colmax[ch][seg][p][xoff] = prev;
        }
    }

    __syncthreads();

    // --- stage 2: 98 threads reduce x-bins across segments, write outputs ---
    const int t = threadIdx.x;
    if (t < CH_PER * POOL * POOL) {                 // 98
        const int chh = t / (POOL * POOL);
        const int pq  = t % (POOL * POOL);
        const int p   = pq / POOL;
        const int q   = pq % POOL;
        const int xs  = (q * Lw) / POOL;
        const int xe  = ((q + 1) * Lw + POOL - 1) / POOL;
        float m = -INFINITY;
        for (int xo = xs; xo < xe; ++xo) {
#pragma unroll
            for (int sg = 0; sg < YS; ++sg)
                m = fmaxf(m, colmax[chh][sg][p][xo]);
        }
        if (!valid) m = 0.0f;
        const int cc = blockIdx.x * CH_PER + chh;
        out[((size_t)bn * Cc + cc) * (POOL * POOL) + pq] = m;
    }
}

extern "C" void kernel_launch(void* const* d_in, const int* in_sizes, int n_in,
                              void* d_out, int out_size, void* d_ws, size_t ws_size,
                              hipStream_t stream) {
    const float* feat  = (const float*)d_in[0];
    const float* boxes = (const float*)d_in[1];
    float* out = (float*)d_out;

    // x = channel pair (fast dim -> XCD round-robin), y = box
    dim3 grid(Cc / CH_PER, Bb * Nn);   // 32 x 256 = 8192 blocks, 8 waves each
    roi_pool_kernel<<<grid, 512, 0, stream>>>(feat, boxes, out);
}

// Round 11
// 27.374 us; speedup vs baseline: 1.3657x; 1.3657x over previous
//
#include <hip/hip_runtime.h>

// ROI max-pooling, faithful to the reference (including the buggy min/max
// ordering). feat: [B=4, C=64, H=128, W=128] f32; boxes: [B, N=64, 7] f32
// out: [B, N, C, 7, 7] f32
//
// Round-11: BIN-SPLIT waves. Block = 512 thr = 8 waves = 2 channels x 4
// bin-groups {01,23,45,6} of one box. Each output bin is produced by exactly
// one wave (adaptive-pool bins overlap by <=1 row; each bin's loop re-reads
// its own boundary row), so there is NO LDS init / combine / state machine
// (what sank round 10). Per wave: R5-style interchanged 2-bin 4-bank load
// pipeline over the group's rows. Max per-wave work drops ~3.4x vs round 7
// -> drain tail shrinks. XCD channel-slicing kept (blockIdx.x%8, 2 MB/XCD).

constexpr int Bb = 4, Cc = 64, Hh = 128, Ww = 128, Nn = 64, BOX_DIM = 7;
constexpr int POOL = 7;
constexpr int CH_PER = 2;           // channels per block
constexpr int PITCH = Ww + 1;       // 129: breaks power-of-2 bank stride

__global__ __launch_bounds__(512) void roi_pool_kernel(
    const float* __restrict__ feat,
    const float* __restrict__ boxes,
    float* __restrict__ out)
{
    __shared__ float colmax[CH_PER][POOL][PITCH];   // 7224 B

    const int bn   = blockIdx.y;                   // box index (B*N)
    const int b    = bn >> 6;                      // Nn = 64
    const int wave = threadIdx.x >> 6;
    const int lane = threadIdx.x & 63;
    const int ch   = wave >> 2;                    // 0..1: channel within pair
    const int g    = wave & 3;                     // bin group 0..3
    const int c    = blockIdx.x * CH_PER + ch;     // channel

    // --- box decode (same address for all lanes -> broadcast load) ---
    const float* bx = boxes + (size_t)bn * BOX_DIM;
    bool valid = false;
#pragma unroll
    for (int i = 0; i < BOX_DIM; ++i) valid = valid || (bx[i] != 0.0f);

    float x1 = fminf(fmaxf(bx[0], 0.0f), (float)(Ww - 1));
    float y1 = fminf(fmaxf(bx[1], 0.0f), (float)(Hh - 1));
    float x2 = fminf(fmaxf(bx[2], 0.0f), (float)(Ww - 1));
    float y2 = fminf(fmaxf(bx[3], 0.0f), (float)(Hh - 1));
    // reference ordering exactly (sequential updates)
    x1 = fminf(x1, x2);
    x2 = fmaxf(x1, x2);
    y1 = fminf(y1, y2);
    y2 = fmaxf(y1, y2);

    // wave-uniform ints -> scalar control flow everywhere below
    int x1i = __builtin_amdgcn_readfirstlane((int)x1);
    int x2i = __builtin_amdgcn_readfirstlane((int)x2);
    int y1i = __builtin_amdgcn_readfirstlane((int)y1);
    int y2i = __builtin_amdgcn_readfirstlane((int)y2);
    if (x2i == x1i) x2i = x1i + 1;
    if (y2i == y1i) y2i = y1i + 1;
    const int Lh = y2i - y1i;      // 1..127
    const int Lw = x2i - x1i;      // 1..127

    // this wave's two bins (group 3 duplicates bin 6; idempotent)
    const int pa = 2 * g;
    const int pb = (g == 3) ? 6 : 2 * g + 1;
    const int sa = y1i + (pa * Lh) / POOL;
    const int ela = y1i + ((pa + 1) * Lh + POOL - 1) / POOL - 1;  // last row
    const int sb = y1i + (pb * Lh) / POOL;
    const int elb = y1i + ((pb + 1) * Lh + POOL - 1) / POOL - 1;
    const int kmax = max(ela - sa, elb - sb) + 1;   // rows in longer bin

    const float* fp = feat + ((size_t)(b * Cc + c) * Hh) * Ww;

    // --- stage 1: per-lane column maxes for this wave's bins ---
    for (int x0 = 0; x0 < Lw; x0 += 64) {
        const int xoff = x0 + lane;                 // < 128 < PITCH
        const int xcol = x1i + min(xoff, Lw - 1);   // clamped, coalesced

        float ma = -INFINITY, mb = -INFINITY;
        // 4 loads in flight: 2 bins x 2 pipeline banks (clamped -> idempotent)
        float fA0 = fp[(size_t)(min(sa + 0, ela) * Ww) + xcol];
        float fA1 = fp[(size_t)(min(sb + 0, elb) * Ww) + xcol];
        float fB0 = fp[(size_t)(min(sa + 1, ela) * Ww) + xcol];
        float fB1 = fp[(size_t)(min(sb + 1, elb) * Ww) + xcol];

        const int kiter = (kmax + 1) >> 1;          // 2 rows/bin per iter
        for (int k = 0; k < kiter; ++k) {
            const int kk = 2 * k;
            float w0 = fA0, w1 = fA1;
            fA0 = fp[(size_t)(min(sa + kk + 2, ela) * Ww) + xcol];
            fA1 = fp[(size_t)(min(sb + kk + 2, elb) * Ww) + xcol];
            ma = fmaxf(ma, w0);
            mb = fmaxf(mb, w1);
            w0 = fB0; w1 = fB1;
            fB0 = fp[(size_t)(min(sa + kk + 3, ela) * Ww) + xcol];
            fB1 = fp[(size_t)(min(sb + kk + 3, elb) * Ww) + xcol];
            ma = fmaxf(ma, w0);
            mb = fmaxf(mb, w1);
        }

        colmax[ch][pa][xoff] = ma;
        colmax[ch][pb][xoff] = mb;   // g==3: same bin, same value (benign)
    }

    __syncthreads();

    // --- stage 2: 98 threads reduce x-bins from LDS, write outputs ---
    const int t = threadIdx.x;
    if (t < CH_PER * POOL * POOL) {                 // 98
        const int chh = t / (POOL * POOL);
        const int pq  = t % (POOL * POOL);
        const int p   = pq / POOL;
        const int q   = pq % POOL;
        const int xs  = (q * Lw) / POOL;
        const int xe  = ((q + 1) * Lw + POOL - 1) / POOL;
        float m = -INFINITY;
        for (int xo = xs; xo < xe; ++xo)
            m = fmaxf(m, colmax[chh][p][xo]);
        if (!valid) m = 0.0f;
        const int cc = blockIdx.x * CH_PER + chh;
        out[((size_t)bn * Cc + cc) * (POOL * POOL) + pq] = m;
    }
}

extern "C" void kernel_launch(void* const* d_in, const int* in_sizes, int n_in,
                              void* d_out, int out_size, void* d_ws, size_t ws_size,
                              hipStream_t stream) {
    const float* feat  = (const float*)d_in[0];
    const float* boxes = (const float*)d_in[1];
    float* out = (float*)d_out;

    // x = channel pair (fast dim -> XCD round-robin), y = box
    dim3 grid(Cc / CH_PER, Bb * Nn);   // 32 x 256 = 8192 blocks, 8 waves each
    roi_pool_kernel<<<grid, 512, 0, stream>>>(feat, boxes, out);
}

// Round 12
// 24.832 us; speedup vs baseline: 1.5056x; 1.1024x over previous
//
#include <hip/hip_runtime.h>

// ROI max-pooling, faithful to the reference (including the buggy min/max
// ordering). feat: [B=4, C=64, H=128, W=128] f32; boxes: [B, N=64, 7] f32
// out: [B, N, C, 7, 7] f32
//
// Round-12: LDS-plane design. Block = one (batch, channel) plane, 256 blocks
// = 1 per CU, 1024 thr = 16 waves. Stage the 64 KB plane into LDS once
// (L2-resident via XCD slicing: gridDim.x = channel -> XCD = c%8), then each
// wave processes 4 boxes ENTIRELY from LDS: float4 row reads (4 rows/instr
// when the ROI fits a 64-col window, else 2 rows/instr full-width), per-bin
// register maxes, __shfl_xor cross-row combine, wave-private LDS scratch for
// the x-bin reduction. Rationale: rounds 7-11 falsified instruction-count /
// dispatch / imbalance theories; the global path appears capped by per-CU
// outstanding-line concurrency (~16 B/cy/CU at L2 latency) -- LDS's dedicated
// 128 B/cy/CU port bypasses it.

constexpr int Bb = 4, Cc = 64, Hh = 128, Ww = 128, Nn = 64, BOX_DIM = 7;
constexpr int POOL = 7;
constexpr int NW = 16;              // waves per block
constexpr int PITCH = 132;          // scratch row pitch (floats), 16B-aligned

__device__ __forceinline__ float4 fmax4(float4 a, float4 b) {
    a.x = fmaxf(a.x, b.x); a.y = fmaxf(a.y, b.y);
    a.z = fmaxf(a.z, b.z); a.w = fmaxf(a.w, b.w);
    return a;
}

// RSTEP = rows per ds_read group (4: 16 lanes x 64-col window; 2: 32 lanes x
// full 128-col width). Two independent b128 loads per iteration (8 or 4 rows)
// to break the LDS latency chain; clamped rows re-read the last row (max is
// idempotent).
template<int RSTEP>
__device__ __forceinline__ void bins_pass(
    const float* plane, float (*scr)[PITCH],
    int y1i, int Lh, int colbase, int lane)
{
    constexpr int NL = 64 / RSTEP;        // lanes per row-group
    const int xi   = lane & (NL - 1);
    const int roff = lane / NL;           // row offset within group
    const int col  = colbase + 4 * xi;

#pragma unroll
    for (int p = 0; p < POOL; ++p) {
        const int s = y1i + (p * Lh) / POOL;
        const int e = y1i + ((p + 1) * Lh + POOL - 1) / POOL;
        float4 pm; pm.x = pm.y = pm.z = pm.w = -INFINITY;
        for (int r = s; r < e; r += 2 * RSTEP) {
            const int row0 = min(r + roff, e - 1);
            const int row1 = min(r + RSTEP + roff, e - 1);
            const float4 v0 = *(const float4*)&plane[row0 * Ww + col];
            const float4 v1 = *(const float4*)&plane[row1 * Ww + col];
            pm = fmax4(pm, fmax4(v0, v1));
        }
        // combine across row-groups (quarters need xor16+xor32, halves xor32)
        if (RSTEP == 4) {
            pm.x = fmaxf(pm.x, __shfl_xor(pm.x, 16));
            pm.y = fmaxf(pm.y, __shfl_xor(pm.y, 16));
            pm.z = fmaxf(pm.z, __shfl_xor(pm.z, 16));
            pm.w = fmaxf(pm.w, __shfl_xor(pm.w, 16));
        }
        pm.x = fmaxf(pm.x, __shfl_xor(pm.x, 32));
        pm.y = fmaxf(pm.y, __shfl_xor(pm.y, 32));
        pm.z = fmaxf(pm.z, __shfl_xor(pm.z, 32));
        pm.w = fmaxf(pm.w, __shfl_xor(pm.w, 32));
        if (lane < NL)
            *(float4*)&scr[p][col] = pm;   // absolute-x slot, 16B aligned
    }
}

__global__ __launch_bounds__(1024) void roi_pool_kernel(
    const float* __restrict__ feat,
    const float* __restrict__ boxes,
    float* __restrict__ out)
{
    __shared__ float plane[Hh * Ww];                 // 65536 B
    __shared__ float scratch[NW][POOL][PITCH];       // 59136 B (124672 total)

    const int c    = blockIdx.x;                     // channel -> XCD = c%8
    const int b    = blockIdx.y;
    const int wv   = threadIdx.x >> 6;
    const int lane = threadIdx.x & 63;

    // ---- stage the (b,c) plane into LDS (coalesced float4) ----
    const float4* fp4 = (const float4*)(feat + (size_t)(b * Cc + c) * (Hh * Ww));
    float4* pl4 = (float4*)plane;
    {
        const int t = threadIdx.x;
        float4 r0 = fp4[t];
        float4 r1 = fp4[t + 1024];
        float4 r2 = fp4[t + 2048];
        float4 r3 = fp4[t + 3072];
        pl4[t] = r0; pl4[t + 1024] = r1; pl4[t + 2048] = r2; pl4[t + 3072] = r3;
    }
    __syncthreads();

    // ---- each wave: 4 boxes, wave-private scratch, no further barriers ----
    for (int j = 0; j < 4; ++j) {
        const int bn = b * Nn + wv + NW * j;         // box index (B*N)
        const float* bx = boxes + (size_t)bn * BOX_DIM;
        bool valid = false;
#pragma unroll
        for (int i = 0; i < BOX_DIM; ++i) valid = valid || (bx[i] != 0.0f);

        float x1 = fminf(fmaxf(bx[0], 0.0f), (float)(Ww - 1));
        float y1 = fminf(fmaxf(bx[1], 0.0f), (float)(Hh - 1));
        float x2 = fminf(fmaxf(bx[2], 0.0f), (float)(Ww - 1));
        float y2 = fminf(fmaxf(bx[3], 0.0f), (float)(Hh - 1));
        // reference ordering exactly (sequential updates)
        x1 = fminf(x1, x2);
        x2 = fmaxf(x1, x2);
        y1 = fminf(y1, y2);
        y2 = fmaxf(y1, y2);

        int x1i = __builtin_amdgcn_readfirstlane((int)x1);
        int x2i = __builtin_amdgcn_readfirstlane((int)x2);
        int y1i = __builtin_amdgcn_readfirstlane((int)y1);
        int y2i = __builtin_amdgcn_readfirstlane((int)y2);
        if (x2i == x1i) x2i += 1;
        if (y2i == y1i) y2i += 1;
        const int Lh = y2i - y1i;      // 1..127
        const int Lw = x2i - x1i;      // 1..127

        // 64-col aligned window; mode A iff it covers the ROI
        const int xa = min(x1i & ~3, Ww - 64);
        if (x2i - xa <= 64)
            bins_pass<4>(plane, scratch[wv], y1i, Lh, xa, lane);
        else
            bins_pass<2>(plane, scratch[wv], y1i, Lh, 0, lane);

        // ---- stage 2: 49 lanes reduce x-bins from scratch, write out ----
        if (lane < POOL * POOL) {
            const int p  = lane / POOL;
            const int q  = lane % POOL;
            const int xs = x1i + (q * Lw) / POOL;
            const int xe = x1i + ((q + 1) * Lw + POOL - 1) / POOL;
            float m = -INFINITY;
            for (int xo = xs; xo < xe; ++xo)
                m = fmaxf(m, scratch[wv][p][xo]);
            if (!valid) m = 0.0f;
            out[((size_t)bn * Cc + c) * (POOL * POOL) + lane] = m;
        }
    }
}

extern "C" void kernel_launch(void* const* d_in, const int* in_sizes, int n_in,
                              void* d_out, int out_size, void* d_ws, size_t ws_size,
                              hipStream_t stream) {
    const float* feat  = (const float*)d_in[0];
    const float* boxes = (const float*)d_in[1];
    float* out = (float*)d_out;

    // x = channel (fast dim -> XCD round-robin), y = batch; 1 block per CU
    dim3 grid(Cc, Bb);   // 64 x 4 = 256 blocks, 1024 threads each
    roi_pool_kernel<<<grid, 1024, 0, stream>>>(feat, boxes, out);
}